// Round 8
// baseline (716.499 us; speedup 1.0000x reference)
//
#include <hip/hip_runtime.h>
#include <hip/hip_bf16.h>

#define N_NODES  50000
#define N_EDGES  800000
#define ND       64
#define ED       32
#define MSGD     128
#define HIDD     256
#define N_AGENTS 25000
#define EPAD     800032   // N_EDGES + 32 (tile padding)

typedef _Float16 f16;
typedef __attribute__((ext_vector_type(4))) _Float16 f16x4;
typedef __attribute__((ext_vector_type(8))) _Float16 f16x8;
typedef __attribute__((ext_vector_type(4))) float f32x4;
typedef unsigned short u16;
typedef unsigned int   u32;
typedef unsigned long long u64;

// ============================================================================
// pack all four weight matrices into fp16 MFMA A-fragment order.
// frag for 16x16x32: lane l, elem j <-> W[k = ks*32 + (l>>4)*8 + j][n = nt*16 + (l&15)]
// ============================================================================
__global__ __launch_bounds__(256) void pack_weights(
    const float* __restrict__ W1, const float* __restrict__ W2,
    const float* __restrict__ Wh1, const float* __restrict__ Wh2,
    f16* __restrict__ F1, f16* __restrict__ F2,
    f16* __restrict__ F3, f16* __restrict__ F4)
{
    int tid  = blockIdx.x * 256 + threadIdx.x;
    int grp  = tid >> 6, lane = tid & 63;
    const float* W; f16* D; int NT, stride, gl;
    if      (grp < 80)  { W = W1;  D = F1; NT = 16; stride = 256; gl = grp; }
    else if (grp < 144) { W = W2;  D = F2; NT = 8;  stride = 128; gl = grp - 80; }
    else if (grp < 208) { W = Wh1; D = F3; NT = 16; stride = 256; gl = grp - 144; }
    else if (grp < 336) { W = Wh2; D = F4; NT = 16; stride = 256; gl = grp - 208; }
    else return;
    int ks = gl / NT, nt = gl - ks * NT;
    int n  = nt * 16 + (lane & 15);
    int k0 = ks * 32 + (lane >> 4) * 8;
    f16* dst = D + ((size_t)gl * 64 + lane) * 8;
    #pragma unroll
    for (int j = 0; j < 8; ++j)
        dst[j] = (f16)W[(size_t)(k0 + j) * stride + n];
}

// ============================================================================
// compact: keep edges with recv < N_AGENTS; degree histogram.
// ============================================================================
__global__ __launch_bounds__(256) void compact_kernel(
    const int* __restrict__ recv, int* __restrict__ elist,
    int* __restrict__ deg, int* __restrict__ cnt)
{
    int i = blockIdx.x * 256 + threadIdx.x;
    int r = recv[i];
    bool keep = (r < N_AGENTS);
    u64 m = __ballot(keep);
    int lane = threadIdx.x & 63;
    int tot = __popcll(m);
    int base = 0;
    if (lane == 0 && tot > 0) base = atomicAdd(cnt, tot);
    base = __shfl(base, 0, 64);
    if (keep) {
        int p = base + __popcll(m & ((1ull << lane) - 1ull));
        elist[p] = i;
        atomicAdd(&deg[r], 1);
    }
}

// ============================================================================
// prefix: exclusive scan deg -> off[25001] + cursor copy (single block)
// ============================================================================
__global__ __launch_bounds__(1024) void prefix_kernel(
    const int* __restrict__ deg, int* __restrict__ off, int* __restrict__ cursor)
{
    __shared__ int part[1024];
    int t = threadIdx.x;
    int i0 = t * 25;
    int s = 0;
    #pragma unroll 1
    for (int i = 0; i < 25; ++i) {
        int idx = i0 + i;
        if (idx < N_AGENTS) s += deg[idx];
    }
    part[t] = s;
    __syncthreads();
    for (int d = 1; d < 1024; d <<= 1) {
        int v = (t >= d) ? part[t - d] : 0;
        __syncthreads();
        part[t] += v;
        __syncthreads();
    }
    int run = (t == 0) ? 0 : part[t - 1];
    #pragma unroll 1
    for (int i = 0; i < 25; ++i) {
        int idx = i0 + i;
        if (idx < N_AGENTS) {
            off[idx] = run; cursor[idx] = run;
            run += deg[idx];
        }
    }
    if (t == 1023) off[N_AGENTS] = part[1023];
}

// ============================================================================
// scatter compacted edges into receiver-sorted position list (eid directly)
// ============================================================================
__global__ __launch_bounds__(256) void scatter_kernel(
    const int* __restrict__ elist, const int* __restrict__ recv,
    const int* __restrict__ cnt, int* __restrict__ cursor, int* __restrict__ eidb)
{
    int n = cnt[0];
    for (int ci = blockIdx.x * 256 + threadIdx.x; ci < n; ci += gridDim.x * 256) {
        int eid = elist[ci];
        int p = atomicAdd(&cursor[recv[eid]], 1);
        eidb[p] = eid;
    }
}

// ============================================================================
// gather/scatter helpers for the edge staging (g fixed per thread)
// ============================================================================
__device__ __forceinline__ float4 gather_item(
    const float4* __restrict__ nf4, const float4* __restrict__ ef4,
    const int* S, const int* R, const int* E, int e, int g)
{
    float4 v;
    if (g < 16)      v = nf4[(size_t)S[e] * 16 + g];
    else if (g < 32) v = nf4[(size_t)R[e] * 16 + (g - 16)];
    else             v = ef4[(size_t)E[e] * 8 + (g - 32)];
    return v;
}
__device__ __forceinline__ void store_item(f16 (*XF)[64][8], int e, int g, float4 v)
{
    int slot = (e >> 4) * 5 + (g >> 3);
    int ln   = (e & 15) + 16 * ((g & 7) >> 1);
    int j0   = (g & 1) * 4;
    f16x4 h;
    h.x = (f16)v.x; h.y = (f16)v.y; h.z = (f16)v.z; h.w = (f16)v.w;
    *(f16x4*)&XF[slot][ln][j0] = h;
}

// ============================================================================
// Edge MLP, fp16 MFMA, weight-stationary, bucket-ordered.
// Register-staged gather pipeline: loads for tile t+1 issue BEFORE layer-1 of
// tile t and land in XF after the layer-1 barrier -> HBM latency hidden behind
// MFMA work. 2 barriers/tile. Biases reloaded at epilogues (saves 16 VGPRs to
// pay for the 12 staging VGPRs; combined regfile stays <=128 -> 4 waves/SIMD).
// ============================================================================
__global__ __launch_bounds__(512, 4) void edge_mlp_mfma(
    const float* __restrict__ nf, const float* __restrict__ ef,
    const f16* __restrict__ F1, const f16* __restrict__ F2,
    const float* __restrict__ b1, const float* __restrict__ b2,
    const float* __restrict__ wg, const float* __restrict__ bg,
    const int* __restrict__ send, const int* __restrict__ recv,
    const int* __restrict__ eidb, const int* __restrict__ cnt,
    f16* __restrict__ msg_out, float* __restrict__ evals)
{
    __shared__ __align__(16) f16 XF[10][64][8];    // 10 KB  (single buffer)
    __shared__ __align__(16) f16 HB[16][64][8];    // 16 KB
    __shared__ __align__(16) f16 msgt[32][136];    // 8.5 KB
    __shared__ float lpart[8][32];
    __shared__ int idxS[32], idxR[32], idxE[32];   // single buffer (barrier-safe)

    const int tid  = threadIdx.x;
    const int wv   = tid >> 6;
    const int lane = tid & 63;
    const int q    = lane >> 4;
    const int li   = lane & 15;
    const int cntv   = cnt[0];
    const int ntiles = (cntv + 31) >> 5;
    const int G      = gridDim.x;
    const float4* nf4 = (const float4*)nf;
    const float4* ef4 = (const float4*)ef;

    // fixed per-thread staging geometry (1280 items: 2 or 3 per thread)
    const int e0i = tid / 40,          g0i = tid - e0i * 40;
    const int e1i = (tid + 512) / 40,  g1i = (tid + 512) - e1i * 40;
    const int e2i = (tid + 1024) / 40, g2i = (tid + 1024) - e2i * 40;  // tid<256 only

    // stationary weight fragments (72 regs)
    f16x8 w1[2][5], w2[8];
    #pragma unroll
    for (int ntl = 0; ntl < 2; ++ntl)
        #pragma unroll
        for (int ks = 0; ks < 5; ++ks)
            w1[ntl][ks] = *(const f16x8*)(F1 + (((size_t)(ks * 16 + 2 * wv + ntl)) * 64 + lane) * 8);
    #pragma unroll
    for (int ks = 0; ks < 8; ++ks)
        w2[ks] = *(const f16x8*)(F2 + (((size_t)(ks * 8 + wv)) * 64 + lane) * 8);

    const int t0 = blockIdx.x;
    // ---- prologue: stage tile t0 into XF; prefetch indices of t0+G ----
    if (t0 < ntiles) {
        if (tid < 32) {
            int eid = eidb[(size_t)t0 * 32 + tid];
            idxE[tid] = eid; idxS[tid] = send[eid]; idxR[tid] = recv[eid];
        }
        __syncthreads();
        float4 p0 = gather_item(nf4, ef4, idxS, idxR, idxE, e0i, g0i);
        float4 p1 = gather_item(nf4, ef4, idxS, idxR, idxE, e1i, g1i);
        float4 p2;
        if (tid < 256) p2 = gather_item(nf4, ef4, idxS, idxR, idxE, e2i, g2i);
        __syncthreads();          // all idx reads done before overwrite
        if (tid < 32 && t0 + G < ntiles) {
            int eid = eidb[(size_t)(t0 + G) * 32 + tid];
            idxE[tid] = eid; idxS[tid] = send[eid]; idxR[tid] = recv[eid];
        }
        store_item(XF, e0i, g0i, p0);
        store_item(XF, e1i, g1i, p1);
        if (tid < 256) store_item(XF, e2i, g2i, p2);
    }
    __syncthreads();

    for (int t = t0; t < ntiles; t += G) {
        const int tp = t + G;
        const bool havep = (tp < ntiles);
        const int e0 = t * 32;

        // ---- phase 0: issue gather loads for tile t+1 (drain in phase 2) ----
        float4 v0, v1, v2;
        if (havep) {
            v0 = gather_item(nf4, ef4, idxS, idxR, idxE, e0i, g0i);
            v1 = gather_item(nf4, ef4, idxS, idxR, idxE, e1i, g1i);
            if (tid < 256) v2 = gather_item(nf4, ef4, idxS, idxR, idxE, e2i, g2i);
        }

        // ---- phase 1: layer 1 h[col][edge] = W1^T x^T (tile t) ----
        f32x4 acc[2][2] = {};   // zero-init; bias added at epilogue
        #pragma unroll
        for (int ks = 0; ks < 5; ++ks)
            #pragma unroll
            for (int eh = 0; eh < 2; ++eh) {
                f16x8 xh = *(const f16x8*)XF[eh * 5 + ks][lane];
                acc[eh][0] = __builtin_amdgcn_mfma_f32_16x16x32_f16(w1[0][ks], xh, acc[eh][0], 0, 0, 0);
                acc[eh][1] = __builtin_amdgcn_mfma_f32_16x16x32_f16(w1[1][ks], xh, acc[eh][1], 0, 0, 0);
            }
        {
            const float4 ba = ((const float4*)b1)[wv * 8 + q];
            const float4 bb = ((const float4*)b1)[wv * 8 + 4 + q];
            #pragma unroll
            for (int eh = 0; eh < 2; ++eh)
                #pragma unroll
                for (int ntl = 0; ntl < 2; ++ntl) {
                    const float4 bv = ntl ? bb : ba;
                    f16x4 hv;
                    hv.x = (f16)fmaxf(acc[eh][ntl][0] + bv.x, 0.f);
                    hv.y = (f16)fmaxf(acc[eh][ntl][1] + bv.y, 0.f);
                    hv.z = (f16)fmaxf(acc[eh][ntl][2] + bv.z, 0.f);
                    hv.w = (f16)fmaxf(acc[eh][ntl][3] + bv.w, 0.f);
                    int l2 = li + 16 * (2 * ntl + (q >> 1));
                    int j0 = (q & 1) * 4;
                    *(f16x4*)&HB[eh * 8 + wv][l2][j0] = hv;
                }
        }
        __syncthreads();   // HB ready; XF free

        // ---- phase 2: land tile t+1 into XF; prefetch indices of t+2 ----
        if (havep) {
            store_item(XF, e0i, g0i, v0);
            store_item(XF, e1i, g1i, v1);
            if (tid < 256) store_item(XF, e2i, g2i, v2);
        }
        if (tid < 32 && tp + G < ntiles) {
            int eid = eidb[(size_t)(tp + G) * 32 + tid];
            idxE[tid] = eid; idxS[tid] = send[eid]; idxR[tid] = recv[eid];
        }

        // ---- phase 3: layer 2 msg[col][edge] = W2^T h^T + gate ----
        f32x4 acc2[2] = {};
        #pragma unroll
        for (int ks2 = 0; ks2 < 8; ++ks2)
            #pragma unroll
            for (int eh = 0; eh < 2; ++eh) {
                f16x8 hh = *(const f16x8*)HB[eh * 8 + ks2][lane];
                acc2[eh] = __builtin_amdgcn_mfma_f32_16x16x32_f16(w2[ks2], hh, acc2[eh], 0, 0, 0);
            }
        {
            const float4 bc  = ((const float4*)b2)[wv * 4 + q];
            const float4 wg4 = ((const float4*)wg)[wv * 4 + q];
            float pr[2];
            #pragma unroll
            for (int eh = 0; eh < 2; ++eh) {
                float x0 = fmaxf(acc2[eh][0] + bc.x, 0.f);
                float x1 = fmaxf(acc2[eh][1] + bc.y, 0.f);
                float x2 = fmaxf(acc2[eh][2] + bc.z, 0.f);
                float x3 = fmaxf(acc2[eh][3] + bc.w, 0.f);
                f16x4 mm;
                mm.x = (f16)x0; mm.y = (f16)x1; mm.z = (f16)x2; mm.w = (f16)x3;
                *(f16x4*)&msgt[eh * 16 + li][wv * 16 + q * 4] = mm;
                float p = x0 * wg4.x + x1 * wg4.y + x2 * wg4.z + x3 * wg4.w;
                p += __shfl_xor(p, 16, 64);
                p += __shfl_xor(p, 32, 64);
                pr[eh] = p;
            }
            if (lane < 16) {
                lpart[wv][li]      = pr[0];
                lpart[wv][16 + li] = pr[1];
            }
        }
        __syncthreads();   // msgt/lpart ready; XF(t+1)/idx(t+2) ready

        // ---- phase 4: writeback msg rows + evals = exp(logit) ----
        {
            int row = tid >> 4, cg = tid & 15;
            *(uint4*)(msg_out + (size_t)(e0 + row) * 128 + cg * 8) =
                *(const uint4*)&msgt[row][cg * 8];
        }
        if (tid < 32) {
            float s2 = bg[0];
            #pragma unroll
            for (int w = 0; w < 8; ++w) s2 += lpart[w][tid];
            evals[e0 + tid] = expf(s2);   // softmax is shift-invariant; |logit|~O(5)
        }
    }
}

// ============================================================================
// Fused CSR softmax-aggregation + agent MLP. 1024 thr, 32 receivers/block.
// Aggregation: 32 threads per receiver, 4 cols each (8 B/lane), sequential
// bucket rows (zero atomics, no aggr round-trip). Then fp16-MFMA 2-layer MLP.
// ============================================================================
__global__ __launch_bounds__(1024, 4) void agg_agent_mfma(
    const int* __restrict__ off, const float* __restrict__ evals,
    const f16* __restrict__ msg,
    const f16* __restrict__ F3, const f16* __restrict__ F4,
    const float* __restrict__ bh1, const float* __restrict__ bh2,
    const float* __restrict__ Wout, const float* __restrict__ bout,
    float* __restrict__ out)
{
    __shared__ __align__(16) f16 XA[8][64][8];     // 8 KB
    __shared__ __align__(16) f16 HB2[16][64][8];   // 16 KB
    __shared__ float lpart[16][32];

    const int tid  = threadIdx.x;
    const int wv   = tid >> 6;
    const int lane = tid & 63;
    const int q    = lane >> 4;
    const int li   = lane & 15;
    const int a0i  = blockIdx.x * 32;

    // ---- aggregation straight into XA fragment layout ----
    {
        int g = tid >> 5, c = tid & 31;   // receiver a0i+g, cols [c*4, c*4+4)
        int r = a0i + g;
        float den = 1e-9f;
        float4 acc = make_float4(0.f, 0.f, 0.f, 0.f);
        if (r < N_AGENTS) {
            int beg = off[r], end = off[r + 1];
            const u64* mp = (const u64*)(msg + (size_t)beg * 128) + c;
            for (int p = beg; p < end; ++p, mp += 32) {
                float e = evals[p];
                den += e;
                union { u64 u; f16 h[4]; } cv; cv.u = *mp;
                acc.x = fmaf(e, (float)cv.h[0], acc.x);
                acc.y = fmaf(e, (float)cv.h[1], acc.y);
                acc.z = fmaf(e, (float)cv.h[2], acc.z);
                acc.w = fmaf(e, (float)cv.h[3], acc.w);
            }
        }
        float inv = 1.0f / den;
        int k0   = c * 4;
        int slot = (g >> 4) * 4 + (k0 >> 5);
        int ln   = (g & 15) + 16 * ((k0 & 31) >> 3);
        int j0   = k0 & 7;
        f16x4 h;
        h.x = (f16)(acc.x * inv); h.y = (f16)(acc.y * inv);
        h.z = (f16)(acc.z * inv); h.w = (f16)(acc.w * inv);
        *(f16x4*)&XA[slot][ln][j0] = h;
    }
    __syncthreads();

    // ---- weight fragments + layer 1 ----
    f16x8 wh1[4], wh2[8];
    #pragma unroll
    for (int ks = 0; ks < 4; ++ks)
        wh1[ks] = *(const f16x8*)(F3 + (((size_t)(ks * 16 + wv)) * 64 + lane) * 8);
    #pragma unroll
    for (int ks = 0; ks < 8; ++ks)
        wh2[ks] = *(const f16x8*)(F4 + (((size_t)(ks * 16 + wv)) * 64 + lane) * 8);

    f32x4 acc[2] = {};
    #pragma unroll
    for (int ks = 0; ks < 4; ++ks)
        #pragma unroll
        for (int eh = 0; eh < 2; ++eh) {
            f16x8 xh = *(const f16x8*)XA[eh * 4 + ks][lane];
            acc[eh] = __builtin_amdgcn_mfma_f32_16x16x32_f16(wh1[ks], xh, acc[eh], 0, 0, 0);
        }
    {
        const float4 b1v = ((const float4*)bh1)[wv * 4 + q];
        #pragma unroll
        for (int eh = 0; eh < 2; ++eh) {
            f16x4 hv;
            hv.x = (f16)fmaxf(acc[eh][0] + b1v.x, 0.f);
            hv.y = (f16)fmaxf(acc[eh][1] + b1v.y, 0.f);
            hv.z = (f16)fmaxf(acc[eh][2] + b1v.z, 0.f);
            hv.w = (f16)fmaxf(acc[eh][3] + b1v.w, 0.f);
            int l2 = li + 16 * ((wv & 1) * 2 + (q >> 1));
            int j0 = (q & 1) * 4;
            *(f16x4*)&HB2[eh * 8 + (wv >> 1)][l2][j0] = hv;
        }
    }
    __syncthreads();

    // ---- layer 2 + output partial ----
    f32x4 acc2[2] = {};
    #pragma unroll
    for (int ks2 = 0; ks2 < 8; ++ks2)
        #pragma unroll
        for (int eh = 0; eh < 2; ++eh) {
            f16x8 hh = *(const f16x8*)HB2[eh * 8 + ks2][lane];
            acc2[eh] = __builtin_amdgcn_mfma_f32_16x16x32_f16(wh2[ks2], hh, acc2[eh], 0, 0, 0);
        }
    {
        const float4 b2v = ((const float4*)bh2)[wv * 4 + q];
        const float4 wo4 = ((const float4*)Wout)[wv * 4 + q];
        float pr[2];
        #pragma unroll
        for (int eh = 0; eh < 2; ++eh) {
            float p = fmaxf(acc2[eh][0] + b2v.x, 0.f) * wo4.x
                    + fmaxf(acc2[eh][1] + b2v.y, 0.f) * wo4.y
                    + fmaxf(acc2[eh][2] + b2v.z, 0.f) * wo4.z
                    + fmaxf(acc2[eh][3] + b2v.w, 0.f) * wo4.w;
            p += __shfl_xor(p, 16, 64);
            p += __shfl_xor(p, 32, 64);
            pr[eh] = p;
        }
        if (lane < 16) {
            lpart[wv][li]      = pr[0];
            lpart[wv][16 + li] = pr[1];
        }
    }
    __syncthreads();

    if (tid < 32 && a0i + tid < N_AGENTS) {
        float s = bout[0];
        #pragma unroll
        for (int w = 0; w < 16; ++w) s += lpart[w][tid];
        out[a0i + tid] = tanhf(s);
    }
}

// ============================================================================
extern "C" void kernel_launch(void* const* d_in, const int* in_sizes, int n_in,
                              void* d_out, int out_size, void* d_ws, size_t ws_size,
                              hipStream_t stream)
{
    const float* nf   = (const float*)d_in[0];
    const float* ef   = (const float*)d_in[1];
    const float* W1   = (const float*)d_in[2];
    const float* b1   = (const float*)d_in[3];
    const float* W2   = (const float*)d_in[4];
    const float* b2   = (const float*)d_in[5];
    const float* wg   = (const float*)d_in[6];
    const float* bg   = (const float*)d_in[7];
    const float* Wh1  = (const float*)d_in[8];
    const float* bh1  = (const float*)d_in[9];
    const float* Wh2  = (const float*)d_in[10];
    const float* bh2  = (const float*)d_in[11];
    const float* Wout = (const float*)d_in[12];
    const float* bout = (const float*)d_in[13];
    const int*   send = (const int*)d_in[14];
    const int*   recv = (const int*)d_in[15];

    // workspace: [cnt|deg|eidb] zeroed, then the rest
    char* ws = (char*)d_ws;
    int* cntp   = (int*)ws;            ws += 16;
    int* deg    = (int*)ws;            ws += (size_t)N_AGENTS * 4;
    int* eidb   = (int*)ws;            ws += (size_t)EPAD * 4;
    size_t zero_bytes = (size_t)(ws - (char*)d_ws);
    int* elist  = (int*)ws;            ws += (size_t)EPAD * 4;
    int* off    = (int*)ws;            ws += (size_t)(N_AGENTS + 8) * 4;
    int* cursor = (int*)ws;            ws += (size_t)N_AGENTS * 4;
    float* evals = (float*)ws;         ws += (size_t)EPAD * 4;
    f16* F1     = (f16*)ws;            ws += (size_t)160 * 256 * 2;
    f16* F2     = (f16*)ws;            ws += (size_t)256 * 128 * 2;
    f16* F3     = (f16*)ws;            ws += (size_t)128 * 256 * 2;
    f16* F4     = (f16*)ws;            ws += (size_t)256 * 256 * 2;
    f16* msg    = (f16*)ws;

    hipMemsetAsync(d_ws, 0, zero_bytes, stream);

    pack_weights<<<84, 256, 0, stream>>>(W1, W2, Wh1, Wh2, F1, F2, F3, F4);
    compact_kernel<<<N_EDGES / 256, 256, 0, stream>>>(recv, elist, deg, cntp);
    prefix_kernel<<<1, 1024, 0, stream>>>(deg, off, cursor);
    scatter_kernel<<<1024, 256, 0, stream>>>(elist, recv, cntp, cursor, eidb);
    edge_mlp_mfma<<<1024, 512, 0, stream>>>(
        nf, ef, F1, F2, b1, b2, wg, bg, send, recv, eidb, cntp, msg, evals);
    agg_agent_mfma<<<(N_AGENTS + 31) / 32, 1024, 0, stream>>>(
        off, evals, msg, F3, F4, bh1, bh2, Wout, bout, (float*)d_out);
}

// Round 9
// 679.854 us; speedup vs baseline: 1.0539x; 1.0539x over previous
//
#include <hip/hip_runtime.h>
#include <hip/hip_bf16.h>

#define N_NODES  50000
#define N_EDGES  800000
#define ND       64
#define ED       32
#define MSGD     128
#define HIDD     256
#define N_AGENTS 25000
#define EPAD     800064   // N_EDGES + 64 (tile padding, M=64)

typedef _Float16 f16;
typedef __attribute__((ext_vector_type(4))) _Float16 f16x4;
typedef __attribute__((ext_vector_type(8))) _Float16 f16x8;
typedef __attribute__((ext_vector_type(4))) float f32x4;
typedef unsigned short u16;
typedef unsigned int   u32;
typedef unsigned long long u64;

// ============================================================================
// pack all four weight matrices into fp16 MFMA A-fragment order.
// frag for 16x16x32: lane l, elem j <-> W[k = ks*32 + (l>>4)*8 + j][n = nt*16 + (l&15)]
// ============================================================================
__global__ __launch_bounds__(256) void pack_weights(
    const float* __restrict__ W1, const float* __restrict__ W2,
    const float* __restrict__ Wh1, const float* __restrict__ Wh2,
    f16* __restrict__ F1, f16* __restrict__ F2,
    f16* __restrict__ F3, f16* __restrict__ F4)
{
    int tid  = blockIdx.x * 256 + threadIdx.x;
    int grp  = tid >> 6, lane = tid & 63;
    const float* W; f16* D; int NT, stride, gl;
    if      (grp < 80)  { W = W1;  D = F1; NT = 16; stride = 256; gl = grp; }
    else if (grp < 144) { W = W2;  D = F2; NT = 8;  stride = 128; gl = grp - 80; }
    else if (grp < 208) { W = Wh1; D = F3; NT = 16; stride = 256; gl = grp - 144; }
    else if (grp < 336) { W = Wh2; D = F4; NT = 16; stride = 256; gl = grp - 208; }
    else return;
    int ks = gl / NT, nt = gl - ks * NT;
    int n  = nt * 16 + (lane & 15);
    int k0 = ks * 32 + (lane >> 4) * 8;
    f16* dst = D + ((size_t)gl * 64 + lane) * 8;
    #pragma unroll
    for (int j = 0; j < 8; ++j)
        dst[j] = (f16)W[(size_t)(k0 + j) * stride + n];
}

// ============================================================================
// compact: keep edges with recv < N_AGENTS; per-receiver rank via atomicAdd.
// ============================================================================
__global__ __launch_bounds__(256) void compact_kernel(
    const int* __restrict__ recv, int* __restrict__ elist,
    int* __restrict__ rlist, int* __restrict__ rankl,
    int* __restrict__ deg, int* __restrict__ cnt)
{
    int i = blockIdx.x * 256 + threadIdx.x;
    int r = recv[i];
    bool keep = (r < N_AGENTS);
    u64 m = __ballot(keep);
    int lane = threadIdx.x & 63;
    int tot = __popcll(m);
    int base = 0;
    if (lane == 0 && tot > 0) base = atomicAdd(cnt, tot);
    base = __shfl(base, 0, 64);
    if (keep) {
        int p = base + __popcll(m & ((1ull << lane) - 1ull));
        int rank = atomicAdd(&deg[r], 1);
        elist[p] = i;
        rlist[p] = r;
        rankl[p] = rank;
    }
}

// ============================================================================
// prefix: exclusive scan deg -> off[25001] (single block)
// ============================================================================
__global__ __launch_bounds__(1024) void prefix_kernel(
    const int* __restrict__ deg, int* __restrict__ off)
{
    __shared__ int part[1024];
    int t = threadIdx.x;
    int i0 = t * 25;
    int s = 0;
    #pragma unroll 1
    for (int i = 0; i < 25; ++i) {
        int idx = i0 + i;
        if (idx < N_AGENTS) s += deg[idx];
    }
    part[t] = s;
    __syncthreads();
    for (int d = 1; d < 1024; d <<= 1) {
        int v = (t >= d) ? part[t - d] : 0;
        __syncthreads();
        part[t] += v;
        __syncthreads();
    }
    int run = (t == 0) ? 0 : part[t - 1];
    #pragma unroll 1
    for (int i = 0; i < 25; ++i) {
        int idx = i0 + i;
        if (idx < N_AGENTS) {
            off[idx] = run;
            run += deg[idx];
        }
    }
    if (t == 1023) off[N_AGENTS] = part[1023];
}

// ============================================================================
// scatter (no atomics): position = off[r] + rank
// ============================================================================
__global__ __launch_bounds__(256) void scatter_kernel(
    const int* __restrict__ elist, const int* __restrict__ rlist,
    const int* __restrict__ rankl, const int* __restrict__ off,
    const int* __restrict__ cnt, int* __restrict__ eidb)
{
    int n = cnt[0];
    for (int ci = blockIdx.x * 256 + threadIdx.x; ci < n; ci += gridDim.x * 256) {
        eidb[off[rlist[ci]] + rankl[ci]] = elist[ci];
    }
}

// ============================================================================
// Edge MLP, fp16 MFMA, weight-stationary, bucket-ordered, M=64 tiles.
// 512 thr = 8 waves, grid 512 (2 blocks/CU, LDS ~73 KB). Consume-immediately
// staging (R4-proven; no register pipeline -> no spills). Looped eh keeps acc
// pressure low. 2 barriers + 1 epilogue barrier per 64 edges.
// ============================================================================
__global__ __launch_bounds__(512, 4) void edge_mlp_mfma(
    const float* __restrict__ nf, const float* __restrict__ ef,
    const f16* __restrict__ F1, const f16* __restrict__ F2,
    const float* __restrict__ b1, const float* __restrict__ b2,
    const float* __restrict__ wg, const float* __restrict__ bg,
    const int* __restrict__ send, const int* __restrict__ recv,
    const int* __restrict__ eidb, const int* __restrict__ cnt,
    f16* __restrict__ msg_out, float* __restrict__ evals)
{
    __shared__ __align__(16) f16 XF[20][64][8];    // 20 KB  slot=(e>>4)*5+ks
    __shared__ __align__(16) f16 HB[32][64][8];    // 32 KB  slot=eh*8+wv(kblk)
    __shared__ __align__(16) f16 msgt[64][136];    // 17 KB
    __shared__ float lpart[8][64];                 // 2 KB

    const int tid  = threadIdx.x;
    const int wv   = tid >> 6;
    const int lane = tid & 63;
    const int q    = lane >> 4;
    const int li   = lane & 15;
    const int cntv   = cnt[0];
    const int ntiles = (cntv + 63) >> 6;
    const int G      = gridDim.x;
    const float4* nf4 = (const float4*)nf;
    const float4* ef4 = (const float4*)ef;

    // stationary weight fragments (72 regs)
    f16x8 w1[2][5], w2[8];
    #pragma unroll
    for (int ntl = 0; ntl < 2; ++ntl)
        #pragma unroll
        for (int ks = 0; ks < 5; ++ks)
            w1[ntl][ks] = *(const f16x8*)(F1 + (((size_t)(ks * 16 + 2 * wv + ntl)) * 64 + lane) * 8);
    #pragma unroll
    for (int ks = 0; ks < 8; ++ks)
        w2[ks] = *(const f16x8*)(F2 + (((size_t)(ks * 8 + wv)) * 64 + lane) * 8);

    const float4 ba  = ((const float4*)b1)[wv * 8 + q];
    const float4 bb  = ((const float4*)b1)[wv * 8 + 4 + q];
    const float4 bc  = ((const float4*)b2)[wv * 4 + q];
    const float4 wg4 = ((const float4*)wg)[wv * 4 + q];
    const float  bgv = bg[0];

    for (int t = blockIdx.x; t < ntiles; t += G) {
        const int e0 = t * 64;

        // ---- stage 64 edges: 2560 float4 items, 5/thread, unrolled chains ----
        #pragma unroll
        for (int it = 0; it < 5; ++it) {
            int idx = tid + it * 512;
            int e = idx / 40, g = idx - e * 40;
            int eid = eidb[e0 + e];            // zero-padded tail -> eid 0 (safe)
            float4 v;
            if (g < 16)      v = nf4[(size_t)send[eid] * 16 + g];
            else if (g < 32) v = nf4[(size_t)recv[eid] * 16 + (g - 16)];
            else             v = ef4[(size_t)eid * 8 + (g - 32)];
            int slot = (e >> 4) * 5 + (g >> 3);
            int ln   = (e & 15) + 16 * ((g & 7) >> 1);
            int j0   = (g & 1) * 4;
            f16x4 h;
            h.x = (f16)v.x; h.y = (f16)v.y; h.z = (f16)v.z; h.w = (f16)v.w;
            *(f16x4*)&XF[slot][ln][j0] = h;
        }
        __syncthreads();

        // ---- layer 1: h[col][edge] = W1^T x^T, eh looped (low reg pressure) ----
        #pragma unroll
        for (int eh = 0; eh < 4; ++eh) {
            f32x4 a0 = f32x4{ba.x, ba.y, ba.z, ba.w};
            f32x4 a1 = f32x4{bb.x, bb.y, bb.z, bb.w};
            #pragma unroll
            for (int ks = 0; ks < 5; ++ks) {
                f16x8 xh = *(const f16x8*)XF[eh * 5 + ks][lane];
                a0 = __builtin_amdgcn_mfma_f32_16x16x32_f16(w1[0][ks], xh, a0, 0, 0, 0);
                a1 = __builtin_amdgcn_mfma_f32_16x16x32_f16(w1[1][ks], xh, a1, 0, 0, 0);
            }
            #pragma unroll
            for (int ntl = 0; ntl < 2; ++ntl) {
                const f32x4& av = ntl ? a1 : a0;
                f16x4 hv;
                hv.x = (f16)fmaxf(av[0], 0.f);
                hv.y = (f16)fmaxf(av[1], 0.f);
                hv.z = (f16)fmaxf(av[2], 0.f);
                hv.w = (f16)fmaxf(av[3], 0.f);
                int l2 = li + 16 * (2 * ntl + (q >> 1));
                int j0 = (q & 1) * 4;
                *(f16x4*)&HB[eh * 8 + wv][l2][j0] = hv;
            }
        }
        __syncthreads();

        // ---- layer 2: msg[col][edge] = W2^T h^T + gate, eh looped ----
        float pr[4];
        #pragma unroll
        for (int eh = 0; eh < 4; ++eh) {
            f32x4 a2 = f32x4{bc.x, bc.y, bc.z, bc.w};
            #pragma unroll
            for (int ks2 = 0; ks2 < 8; ++ks2) {
                f16x8 hh = *(const f16x8*)HB[eh * 8 + ks2][lane];
                a2 = __builtin_amdgcn_mfma_f32_16x16x32_f16(w2[ks2], hh, a2, 0, 0, 0);
            }
            float x0 = fmaxf(a2[0], 0.f);
            float x1 = fmaxf(a2[1], 0.f);
            float x2 = fmaxf(a2[2], 0.f);
            float x3 = fmaxf(a2[3], 0.f);
            f16x4 mm;
            mm.x = (f16)x0; mm.y = (f16)x1; mm.z = (f16)x2; mm.w = (f16)x3;
            *(f16x4*)&msgt[eh * 16 + li][wv * 16 + q * 4] = mm;
            float p = x0 * wg4.x + x1 * wg4.y + x2 * wg4.z + x3 * wg4.w;
            p += __shfl_xor(p, 16, 64);
            p += __shfl_xor(p, 32, 64);
            pr[eh] = p;
        }
        if (lane < 16) {
            #pragma unroll
            for (int eh = 0; eh < 4; ++eh) lpart[wv][eh * 16 + li] = pr[eh];
        }
        __syncthreads();

        // ---- writeback: 64 coalesced msg rows + evals = exp(logit) ----
        #pragma unroll
        for (int it = 0; it < 2; ++it) {
            int idx = tid + it * 512;
            int row = idx >> 4, cg = idx & 15;
            *(uint4*)(msg_out + (size_t)(e0 + row) * 128 + cg * 8) =
                *(const uint4*)&msgt[row][cg * 8];
        }
        if (tid < 64) {
            float s2 = bgv;
            #pragma unroll
            for (int w = 0; w < 8; ++w) s2 += lpart[w][tid];
            evals[e0 + tid] = expf(s2);   // softmax shift-invariant; |logit|~O(5)
        }
        __syncthreads();   // protect msgt/lpart/XF before next tile
    }
}

// ============================================================================
// Fused CSR softmax-aggregation + agent MLP. 1024 thr, 32 receivers/block.
// ============================================================================
__global__ __launch_bounds__(1024, 4) void agg_agent_mfma(
    const int* __restrict__ off, const float* __restrict__ evals,
    const f16* __restrict__ msg,
    const f16* __restrict__ F3, const f16* __restrict__ F4,
    const float* __restrict__ bh1, const float* __restrict__ bh2,
    const float* __restrict__ Wout, const float* __restrict__ bout,
    float* __restrict__ out)
{
    __shared__ __align__(16) f16 XA[8][64][8];     // 8 KB
    __shared__ __align__(16) f16 HB2[16][64][8];   // 16 KB
    __shared__ float lpart[16][32];

    const int tid  = threadIdx.x;
    const int wv   = tid >> 6;
    const int lane = tid & 63;
    const int q    = lane >> 4;
    const int li   = lane & 15;
    const int a0i  = blockIdx.x * 32;

    // ---- aggregation straight into XA fragment layout ----
    {
        int g = tid >> 5, c = tid & 31;   // receiver a0i+g, cols [c*4, c*4+4)
        int r = a0i + g;
        float den = 1e-9f;
        float4 acc = make_float4(0.f, 0.f, 0.f, 0.f);
        if (r < N_AGENTS) {
            int beg = off[r], end = off[r + 1];
            const u64* mp = (const u64*)(msg + (size_t)beg * 128) + c;
            for (int p = beg; p < end; ++p, mp += 32) {
                float e = evals[p];
                den += e;
                union { u64 u; f16 h[4]; } cv; cv.u = *mp;
                acc.x = fmaf(e, (float)cv.h[0], acc.x);
                acc.y = fmaf(e, (float)cv.h[1], acc.y);
                acc.z = fmaf(e, (float)cv.h[2], acc.z);
                acc.w = fmaf(e, (float)cv.h[3], acc.w);
            }
        }
        float inv = 1.0f / den;
        int k0   = c * 4;
        int slot = (g >> 4) * 4 + (k0 >> 5);
        int ln   = (g & 15) + 16 * ((k0 & 31) >> 3);
        int j0   = k0 & 7;
        f16x4 h;
        h.x = (f16)(acc.x * inv); h.y = (f16)(acc.y * inv);
        h.z = (f16)(acc.z * inv); h.w = (f16)(acc.w * inv);
        *(f16x4*)&XA[slot][ln][j0] = h;
    }
    __syncthreads();

    // ---- weight fragments + layer 1 ----
    f16x8 wh1[4], wh2[8];
    #pragma unroll
    for (int ks = 0; ks < 4; ++ks)
        wh1[ks] = *(const f16x8*)(F3 + (((size_t)(ks * 16 + wv)) * 64 + lane) * 8);
    #pragma unroll
    for (int ks = 0; ks < 8; ++ks)
        wh2[ks] = *(const f16x8*)(F4 + (((size_t)(ks * 16 + wv)) * 64 + lane) * 8);

    f32x4 acc[2] = {};
    #pragma unroll
    for (int ks = 0; ks < 4; ++ks)
        #pragma unroll
        for (int eh = 0; eh < 2; ++eh) {
            f16x8 xh = *(const f16x8*)XA[eh * 4 + ks][lane];
            acc[eh] = __builtin_amdgcn_mfma_f32_16x16x32_f16(wh1[ks], xh, acc[eh], 0, 0, 0);
        }
    {
        const float4 b1v = ((const float4*)bh1)[wv * 4 + q];
        #pragma unroll
        for (int eh = 0; eh < 2; ++eh) {
            f16x4 hv;
            hv.x = (f16)fmaxf(acc[eh][0] + b1v.x, 0.f);
            hv.y = (f16)fmaxf(acc[eh][1] + b1v.y, 0.f);
            hv.z = (f16)fmaxf(acc[eh][2] + b1v.z, 0.f);
            hv.w = (f16)fmaxf(acc[eh][3] + b1v.w, 0.f);
            int l2 = li + 16 * ((wv & 1) * 2 + (q >> 1));
            int j0 = (q & 1) * 4;
            *(f16x4*)&HB2[eh * 8 + (wv >> 1)][l2][j0] = hv;
        }
    }
    __syncthreads();

    // ---- layer 2 + output partial ----
    f32x4 acc2[2] = {};
    #pragma unroll
    for (int ks2 = 0; ks2 < 8; ++ks2)
        #pragma unroll
        for (int eh = 0; eh < 2; ++eh) {
            f16x8 hh = *(const f16x8*)HB2[eh * 8 + ks2][lane];
            acc2[eh] = __builtin_amdgcn_mfma_f32_16x16x32_f16(wh2[ks2], hh, acc2[eh], 0, 0, 0);
        }
    {
        const float4 b2v = ((const float4*)bh2)[wv * 4 + q];
        const float4 wo4 = ((const float4*)Wout)[wv * 4 + q];
        float pr[2];
        #pragma unroll
        for (int eh = 0; eh < 2; ++eh) {
            float p = fmaxf(acc2[eh][0] + b2v.x, 0.f) * wo4.x
                    + fmaxf(acc2[eh][1] + b2v.y, 0.f) * wo4.y
                    + fmaxf(acc2[eh][2] + b2v.z, 0.f) * wo4.z
                    + fmaxf(acc2[eh][3] + b2v.w, 0.f) * wo4.w;
            p += __shfl_xor(p, 16, 64);
            p += __shfl_xor(p, 32, 64);
            pr[eh] = p;
        }
        if (lane < 16) {
            lpart[wv][li]      = pr[0];
            lpart[wv][16 + li] = pr[1];
        }
    }
    __syncthreads();

    if (tid < 32 && a0i + tid < N_AGENTS) {
        float s = bout[0];
        #pragma unroll
        for (int w = 0; w < 16; ++w) s += lpart[w][tid];
        out[a0i + tid] = tanhf(s);
    }
}

// ============================================================================
extern "C" void kernel_launch(void* const* d_in, const int* in_sizes, int n_in,
                              void* d_out, int out_size, void* d_ws, size_t ws_size,
                              hipStream_t stream)
{
    const float* nf   = (const float*)d_in[0];
    const float* ef   = (const float*)d_in[1];
    const float* W1   = (const float*)d_in[2];
    const float* b1   = (const float*)d_in[3];
    const float* W2   = (const float*)d_in[4];
    const float* b2   = (const float*)d_in[5];
    const float* wg   = (const float*)d_in[6];
    const float* bg   = (const float*)d_in[7];
    const float* Wh1  = (const float*)d_in[8];
    const float* bh1  = (const float*)d_in[9];
    const float* Wh2  = (const float*)d_in[10];
    const float* bh2  = (const float*)d_in[11];
    const float* Wout = (const float*)d_in[12];
    const float* bout = (const float*)d_in[13];
    const int*   send = (const int*)d_in[14];
    const int*   recv = (const int*)d_in[15];

    // workspace: [cnt|deg|eidb] zeroed, then the rest
    char* ws = (char*)d_ws;
    int* cntp   = (int*)ws;            ws += 16;
    int* deg    = (int*)ws;            ws += (size_t)N_AGENTS * 4;
    int* eidb   = (int*)ws;            ws += (size_t)EPAD * 4;
    size_t zero_bytes = (size_t)(ws - (char*)d_ws);
    int* elist  = (int*)ws;            ws += (size_t)EPAD * 4;
    int* rlist  = (int*)ws;            ws += (size_t)EPAD * 4;
    int* rankl  = (int*)ws;            ws += (size_t)EPAD * 4;
    int* off    = (int*)ws;            ws += (size_t)(N_AGENTS + 8) * 4;
    float* evals = (float*)ws;         ws += (size_t)EPAD * 4;
    f16* F1     = (f16*)ws;            ws += (size_t)160 * 256 * 2;
    f16* F2     = (f16*)ws;            ws += (size_t)256 * 128 * 2;
    f16* F3     = (f16*)ws;            ws += (size_t)128 * 256 * 2;
    f16* F4     = (f16*)ws;            ws += (size_t)256 * 256 * 2;
    f16* msg    = (f16*)ws;

    hipMemsetAsync(d_ws, 0, zero_bytes, stream);

    pack_weights<<<84, 256, 0, stream>>>(W1, W2, Wh1, Wh2, F1, F2, F3, F4);
    compact_kernel<<<N_EDGES / 256, 256, 0, stream>>>(
        recv, elist, rlist, rankl, deg, cntp);
    prefix_kernel<<<1, 1024, 0, stream>>>(deg, off);
    scatter_kernel<<<1024, 256, 0, stream>>>(elist, rlist, rankl, off, cntp, eidb);
    edge_mlp_mfma<<<512, 512, 0, stream>>>(
        nf, ef, F1, F2, b1, b2, wg, bg, send, recv, eidb, cntp, msg, evals);
    agg_agent_mfma<<<(N_AGENTS + 31) / 32, 1024, 0, stream>>>(
        off, evals, msg, F3, F4, bh1, bh2, Wout, bout, (float*)d_out);
}

// Round 10
// 592.519 us; speedup vs baseline: 1.2092x; 1.1474x over previous
//
#include <hip/hip_runtime.h>
#include <hip/hip_bf16.h>

#define N_NODES  50000
#define N_EDGES  800000
#define ND       64
#define ED       32
#define MSGD     128
#define HIDD     256
#define N_AGENTS 25000
#define EPAD     800064   // N_EDGES + 64 (tile padding)

typedef _Float16 f16;
typedef __attribute__((ext_vector_type(4))) _Float16 f16x4;
typedef __attribute__((ext_vector_type(8))) _Float16 f16x8;
typedef __attribute__((ext_vector_type(4))) float f32x4;
typedef unsigned short u16;
typedef unsigned int   u32;
typedef unsigned long long u64;

// ============================================================================
// pack all four weight matrices into fp16 MFMA A-fragment order.
// frag for 16x16x32: lane l, elem j <-> W[k = ks*32 + (l>>4)*8 + j][n = nt*16 + (l&15)]
// ============================================================================
__global__ __launch_bounds__(256) void pack_weights(
    const float* __restrict__ W1, const float* __restrict__ W2,
    const float* __restrict__ Wh1, const float* __restrict__ Wh2,
    f16* __restrict__ F1, f16* __restrict__ F2,
    f16* __restrict__ F3, f16* __restrict__ F4)
{
    int tid  = blockIdx.x * 256 + threadIdx.x;
    int grp  = tid >> 6, lane = tid & 63;
    const float* W; f16* D; int NT, stride, gl;
    if      (grp < 80)  { W = W1;  D = F1; NT = 16; stride = 256; gl = grp; }
    else if (grp < 144) { W = W2;  D = F2; NT = 8;  stride = 128; gl = grp - 80; }
    else if (grp < 208) { W = Wh1; D = F3; NT = 16; stride = 256; gl = grp - 144; }
    else if (grp < 336) { W = Wh2; D = F4; NT = 16; stride = 256; gl = grp - 208; }
    else return;
    int ks = gl / NT, nt = gl - ks * NT;
    int n  = nt * 16 + (lane & 15);
    int k0 = ks * 32 + (lane >> 4) * 8;
    f16* dst = D + ((size_t)gl * 64 + lane) * 8;
    #pragma unroll
    for (int j = 0; j < 8; ++j)
        dst[j] = (f16)W[(size_t)(k0 + j) * stride + n];
}

// ============================================================================
// compact: keep edges with recv < N_AGENTS; per-receiver rank via atomicAdd.
// ============================================================================
__global__ __launch_bounds__(256) void compact_kernel(
    const int* __restrict__ recv, int* __restrict__ elist,
    int* __restrict__ rlist, int* __restrict__ rankl,
    int* __restrict__ deg, int* __restrict__ cnt)
{
    int i = blockIdx.x * 256 + threadIdx.x;
    int r = recv[i];
    bool keep = (r < N_AGENTS);
    u64 m = __ballot(keep);
    int lane = threadIdx.x & 63;
    int tot = __popcll(m);
    int base = 0;
    if (lane == 0 && tot > 0) base = atomicAdd(cnt, tot);
    base = __shfl(base, 0, 64);
    if (keep) {
        int p = base + __popcll(m & ((1ull << lane) - 1ull));
        int rank = atomicAdd(&deg[r], 1);
        elist[p] = i;
        rlist[p] = r;
        rankl[p] = rank;
    }
}

// ============================================================================
// prefix: exclusive scan deg -> off[25001] (single block)
// ============================================================================
__global__ __launch_bounds__(1024) void prefix_kernel(
    const int* __restrict__ deg, int* __restrict__ off)
{
    __shared__ int part[1024];
    int t = threadIdx.x;
    int i0 = t * 25;
    int s = 0;
    #pragma unroll 1
    for (int i = 0; i < 25; ++i) {
        int idx = i0 + i;
        if (idx < N_AGENTS) s += deg[idx];
    }
    part[t] = s;
    __syncthreads();
    for (int d = 1; d < 1024; d <<= 1) {
        int v = (t >= d) ? part[t - d] : 0;
        __syncthreads();
        part[t] += v;
        __syncthreads();
    }
    int run = (t == 0) ? 0 : part[t - 1];
    #pragma unroll 1
    for (int i = 0; i < 25; ++i) {
        int idx = i0 + i;
        if (idx < N_AGENTS) {
            off[idx] = run;
            run += deg[idx];
        }
    }
    if (t == 1023) off[N_AGENTS] = part[1023];
}

// ============================================================================
// scatter (no atomics): position = off[r] + rank
// ============================================================================
__global__ __launch_bounds__(256) void scatter_kernel(
    const int* __restrict__ elist, const int* __restrict__ rlist,
    const int* __restrict__ rankl, const int* __restrict__ off,
    const int* __restrict__ cnt, int* __restrict__ eidb)
{
    int n = cnt[0];
    for (int ci = blockIdx.x * 256 + threadIdx.x; ci < n; ci += gridDim.x * 256) {
        eidb[off[rlist[ci]] + rankl[ci]] = elist[ci];
    }
}

// ============================================================================
// Edge MLP — EXACT R4 structure (measured optimum: 196 us, FETCH 119 MB).
// fp16 MFMA, weight-stationary, bucket-ordered, M=32 tiles, 512 thr = 8 waves,
// grid 512, 3 barriers/tile, direct-eid staging idiom (do not restructure:
// R8/R9 variants blow FETCH to 450-514 MB). Only delta vs R4: evals=exp(logit).
// ============================================================================
__global__ __launch_bounds__(512, 4) void edge_mlp_mfma(
    const float* __restrict__ nf, const float* __restrict__ ef,
    const f16* __restrict__ F1, const f16* __restrict__ F2,
    const float* __restrict__ b1, const float* __restrict__ b2,
    const float* __restrict__ wg, const float* __restrict__ bg,
    const int* __restrict__ send, const int* __restrict__ recv,
    const int* __restrict__ eidb, const int* __restrict__ cnt,
    f16* __restrict__ msg_out, float* __restrict__ evals)
{
    __shared__ __align__(16) f16 XF[10][64][8];    // 10 KB
    __shared__ __align__(16) f16 HB[16][64][8];    // 16 KB
    __shared__ __align__(16) f16 msgt[32][136];    // 8.5 KB
    __shared__ float lpart[8][32];

    const int tid  = threadIdx.x;
    const int wv   = tid >> 6;
    const int lane = tid & 63;
    const int q    = lane >> 4;
    const int li   = lane & 15;
    const int cntv   = cnt[0];
    const int ntiles = (cntv + 31) >> 5;
    const int G      = gridDim.x;

    // stationary weight fragments: W1 2 col-tiles + W2 1 col-tile per wave
    f16x8 w1[2][5], w2[8];
    #pragma unroll
    for (int ntl = 0; ntl < 2; ++ntl)
        #pragma unroll
        for (int ks = 0; ks < 5; ++ks)
            w1[ntl][ks] = *(const f16x8*)(F1 + (((size_t)(ks * 16 + 2 * wv + ntl)) * 64 + lane) * 8);
    #pragma unroll
    for (int ks = 0; ks < 8; ++ks)
        w2[ks] = *(const f16x8*)(F2 + (((size_t)(ks * 8 + wv)) * 64 + lane) * 8);

    const float4 ba  = *(const float4*)&b1[wv * 32 + q * 4];
    const float4 bb  = *(const float4*)&b1[wv * 32 + 16 + q * 4];
    const float4 bc  = *(const float4*)&b2[wv * 16 + q * 4];
    const float4 wg4 = *(const float4*)&wg[wv * 16 + q * 4];
    const float  bgv = bg[0];

    for (int t = blockIdx.x; t < ntiles; t += G) {
        const int e0 = t * 32;

        // ---- stage x = [nf[s]|nf[r]|ef] -> fp16 B-frag order ----
        for (int idx = tid; idx < 1280; idx += 512) {
            int e = idx / 40, g = idx - e * 40;
            int eid = eidb[e0 + e];
            float4 v;
            if (g < 16)      v = ((const float4*)nf)[(size_t)send[eid] * 16 + g];
            else if (g < 32) v = ((const float4*)nf)[(size_t)recv[eid] * 16 + (g - 16)];
            else             v = ((const float4*)ef)[(size_t)eid * 8 + (g - 32)];
            int k0   = g * 4;
            int slot = (e >> 4) * 5 + (k0 >> 5);
            int ln   = (e & 15) + 16 * ((k0 & 31) >> 3);
            int j0   = k0 & 7;
            f16x4 h;
            h.x = (f16)v.x; h.y = (f16)v.y; h.z = (f16)v.z; h.w = (f16)v.w;
            *(f16x4*)&XF[slot][ln][j0] = h;
        }
        __syncthreads();

        // ---- layer 1: h[col][edge] = W1^T x^T ----
        f32x4 acc[2][2];   // [eh][ntl]
        acc[0][0] = f32x4{ba.x, ba.y, ba.z, ba.w}; acc[1][0] = acc[0][0];
        acc[0][1] = f32x4{bb.x, bb.y, bb.z, bb.w}; acc[1][1] = acc[0][1];
        #pragma unroll
        for (int ks = 0; ks < 5; ++ks)
            #pragma unroll
            for (int eh = 0; eh < 2; ++eh) {
                f16x8 xh = *(const f16x8*)XF[eh * 5 + ks][lane];
                acc[eh][0] = __builtin_amdgcn_mfma_f32_16x16x32_f16(w1[0][ks], xh, acc[eh][0], 0, 0, 0);
                acc[eh][1] = __builtin_amdgcn_mfma_f32_16x16x32_f16(w1[1][ks], xh, acc[eh][1], 0, 0, 0);
            }
        // relu + stash h as layer-2 B frags
        #pragma unroll
        for (int eh = 0; eh < 2; ++eh)
            #pragma unroll
            for (int ntl = 0; ntl < 2; ++ntl) {
                f16x4 hv;
                hv.x = (f16)fmaxf(acc[eh][ntl][0], 0.f);
                hv.y = (f16)fmaxf(acc[eh][ntl][1], 0.f);
                hv.z = (f16)fmaxf(acc[eh][ntl][2], 0.f);
                hv.w = (f16)fmaxf(acc[eh][ntl][3], 0.f);
                int l2 = li + 16 * (2 * ntl + (q >> 1));
                int j0 = (q & 1) * 4;
                *(f16x4*)&HB[eh * 8 + wv][l2][j0] = hv;
            }
        __syncthreads();

        // ---- layer 2: msg[col][edge] = W2^T h^T ----
        f32x4 acc2[2];
        acc2[0] = f32x4{bc.x, bc.y, bc.z, bc.w}; acc2[1] = acc2[0];
        #pragma unroll
        for (int ks2 = 0; ks2 < 8; ++ks2)
            #pragma unroll
            for (int eh = 0; eh < 2; ++eh) {
                f16x8 hh = *(const f16x8*)HB[eh * 8 + ks2][lane];
                acc2[eh] = __builtin_amdgcn_mfma_f32_16x16x32_f16(w2[ks2], hh, acc2[eh], 0, 0, 0);
            }
        // relu + gate partial + msg stash
        {
            float pr[2];
            #pragma unroll
            for (int eh = 0; eh < 2; ++eh) {
                float v0 = fmaxf(acc2[eh][0], 0.f);
                float v1 = fmaxf(acc2[eh][1], 0.f);
                float v2 = fmaxf(acc2[eh][2], 0.f);
                float v3 = fmaxf(acc2[eh][3], 0.f);
                f16x4 mm;
                mm.x = (f16)v0; mm.y = (f16)v1; mm.z = (f16)v2; mm.w = (f16)v3;
                *(f16x4*)&msgt[eh * 16 + li][wv * 16 + q * 4] = mm;
                float p = v0 * wg4.x + v1 * wg4.y + v2 * wg4.z + v3 * wg4.w;
                p += __shfl_xor(p, 16, 64);
                p += __shfl_xor(p, 32, 64);
                pr[eh] = p;
            }
            if (lane < 16) {
                lpart[wv][li]      = pr[0];
                lpart[wv][16 + li] = pr[1];
            }
        }
        __syncthreads();

        // ---- writeback: coalesced msg rows + evals = exp(logit) ----
        {
            int row = tid >> 4, cg = tid & 15;
            *(uint4*)(msg_out + (size_t)(e0 + row) * 128 + cg * 8) =
                *(const uint4*)&msgt[row][cg * 8];
        }
        if (tid < 32) {
            float s2 = bgv;
            #pragma unroll
            for (int w = 0; w < 8; ++w) s2 += lpart[w][tid];
            evals[e0 + tid] = expf(s2);   // softmax shift-invariant; |logit|~O(5)
        }
    }
}

// ============================================================================
// Fused CSR softmax-aggregation + agent MLP. 1024 thr, 32 receivers/block.
// Aggregation: 32 threads per receiver, 4 cols each (8 B/lane), sequential
// bucket rows (zero atomics, no aggr round-trip). Then fp16-MFMA 2-layer MLP.
// ============================================================================
__global__ __launch_bounds__(1024, 4) void agg_agent_mfma(
    const int* __restrict__ off, const float* __restrict__ evals,
    const f16* __restrict__ msg,
    const f16* __restrict__ F3, const f16* __restrict__ F4,
    const float* __restrict__ bh1, const float* __restrict__ bh2,
    const float* __restrict__ Wout, const float* __restrict__ bout,
    float* __restrict__ out)
{
    __shared__ __align__(16) f16 XA[8][64][8];     // 8 KB
    __shared__ __align__(16) f16 HB2[16][64][8];   // 16 KB
    __shared__ float lpart[16][32];

    const int tid  = threadIdx.x;
    const int wv   = tid >> 6;
    const int lane = tid & 63;
    const int q    = lane >> 4;
    const int li   = lane & 15;
    const int a0i  = blockIdx.x * 32;

    // ---- aggregation straight into XA fragment layout ----
    {
        int g = tid >> 5, c = tid & 31;   // receiver a0i+g, cols [c*4, c*4+4)
        int r = a0i + g;
        float den = 1e-9f;
        float4 acc = make_float4(0.f, 0.f, 0.f, 0.f);
        if (r < N_AGENTS) {
            int beg = off[r], end = off[r + 1];
            const u64* mp = (const u64*)(msg + (size_t)beg * 128) + c;
            for (int p = beg; p < end; ++p, mp += 32) {
                float e = evals[p];
                den += e;
                union { u64 u; f16 h[4]; } cv; cv.u = *mp;
                acc.x = fmaf(e, (float)cv.h[0], acc.x);
                acc.y = fmaf(e, (float)cv.h[1], acc.y);
                acc.z = fmaf(e, (float)cv.h[2], acc.z);
                acc.w = fmaf(e, (float)cv.h[3], acc.w);
            }
        }
        float inv = 1.0f / den;
        int k0   = c * 4;
        int slot = (g >> 4) * 4 + (k0 >> 5);
        int ln   = (g & 15) + 16 * ((k0 & 31) >> 3);
        int j0   = k0 & 7;
        f16x4 h;
        h.x = (f16)(acc.x * inv); h.y = (f16)(acc.y * inv);
        h.z = (f16)(acc.z * inv); h.w = (f16)(acc.w * inv);
        *(f16x4*)&XA[slot][ln][j0] = h;
    }
    __syncthreads();

    // ---- weight fragments + layer 1 ----
    f16x8 wh1[4], wh2[8];
    #pragma unroll
    for (int ks = 0; ks < 4; ++ks)
        wh1[ks] = *(const f16x8*)(F3 + (((size_t)(ks * 16 + wv)) * 64 + lane) * 8);
    #pragma unroll
    for (int ks = 0; ks < 8; ++ks)
        wh2[ks] = *(const f16x8*)(F4 + (((size_t)(ks * 16 + wv)) * 64 + lane) * 8);

    f32x4 acc[2] = {};
    #pragma unroll
    for (int ks = 0; ks < 4; ++ks)
        #pragma unroll
        for (int eh = 0; eh < 2; ++eh) {
            f16x8 xh = *(const f16x8*)XA[eh * 4 + ks][lane];
            acc[eh] = __builtin_amdgcn_mfma_f32_16x16x32_f16(wh1[ks], xh, acc[eh], 0, 0, 0);
        }
    {
        const float4 b1v = ((const float4*)bh1)[wv * 4 + q];
        #pragma unroll
        for (int eh = 0; eh < 2; ++eh) {
            f16x4 hv;
            hv.x = (f16)fmaxf(acc[eh][0] + b1v.x, 0.f);
            hv.y = (f16)fmaxf(acc[eh][1] + b1v.y, 0.f);
            hv.z = (f16)fmaxf(acc[eh][2] + b1v.z, 0.f);
            hv.w = (f16)fmaxf(acc[eh][3] + b1v.w, 0.f);
            int l2 = li + 16 * ((wv & 1) * 2 + (q >> 1));
            int j0 = (q & 1) * 4;
            *(f16x4*)&HB2[eh * 8 + (wv >> 1)][l2][j0] = hv;
        }
    }
    __syncthreads();

    // ---- layer 2 + output partial ----
    f32x4 acc2[2] = {};
    #pragma unroll
    for (int ks2 = 0; ks2 < 8; ++ks2)
        #pragma unroll
        for (int eh = 0; eh < 2; ++eh) {
            f16x8 hh = *(const f16x8*)HB2[eh * 8 + ks2][lane];
            acc2[eh] = __builtin_amdgcn_mfma_f32_16x16x32_f16(wh2[ks2], hh, acc2[eh], 0, 0, 0);
        }
    {
        const float4 b2v = ((const float4*)bh2)[wv * 4 + q];
        const float4 wo4 = ((const float4*)Wout)[wv * 4 + q];
        float pr[2];
        #pragma unroll
        for (int eh = 0; eh < 2; ++eh) {
            float p = fmaxf(acc2[eh][0] + b2v.x, 0.f) * wo4.x
                    + fmaxf(acc2[eh][1] + b2v.y, 0.f) * wo4.y
                    + fmaxf(acc2[eh][2] + b2v.z, 0.f) * wo4.z
                    + fmaxf(acc2[eh][3] + b2v.w, 0.f) * wo4.w;
            p += __shfl_xor(p, 16, 64);
            p += __shfl_xor(p, 32, 64);
            pr[eh] = p;
        }
        if (lane < 16) {
            lpart[wv][li]      = pr[0];
            lpart[wv][16 + li] = pr[1];
        }
    }
    __syncthreads();

    if (tid < 32 && a0i + tid < N_AGENTS) {
        float s = bout[0];
        #pragma unroll
        for (int w = 0; w < 16; ++w) s += lpart[w][tid];
        out[a0i + tid] = tanhf(s);
    }
}

// ============================================================================
extern "C" void kernel_launch(void* const* d_in, const int* in_sizes, int n_in,
                              void* d_out, int out_size, void* d_ws, size_t ws_size,
                              hipStream_t stream)
{
    const float* nf   = (const float*)d_in[0];
    const float* ef   = (const float*)d_in[1];
    const float* W1   = (const float*)d_in[2];
    const float* b1   = (const float*)d_in[3];
    const float* W2   = (const float*)d_in[4];
    const float* b2   = (const float*)d_in[5];
    const float* wg   = (const float*)d_in[6];
    const float* bg   = (const float*)d_in[7];
    const float* Wh1  = (const float*)d_in[8];
    const float* bh1  = (const float*)d_in[9];
    const float* Wh2  = (const float*)d_in[10];
    const float* bh2  = (const float*)d_in[11];
    const float* Wout = (const float*)d_in[12];
    const float* bout = (const float*)d_in[13];
    const int*   send = (const int*)d_in[14];
    const int*   recv = (const int*)d_in[15];

    // workspace: [cnt|deg|eidb] zeroed, then the rest
    char* ws = (char*)d_ws;
    int* cntp   = (int*)ws;            ws += 16;
    int* deg    = (int*)ws;            ws += (size_t)N_AGENTS * 4;
    int* eidb   = (int*)ws;            ws += (size_t)EPAD * 4;
    size_t zero_bytes = (size_t)(ws - (char*)d_ws);
    int* elist  = (int*)ws;            ws += (size_t)EPAD * 4;
    int* rlist  = (int*)ws;            ws += (size_t)EPAD * 4;
    int* rankl  = (int*)ws;            ws += (size_t)EPAD * 4;
    int* off    = (int*)ws;            ws += (size_t)(N_AGENTS + 8) * 4;
    float* evals = (float*)ws;         ws += (size_t)EPAD * 4;
    f16* F1     = (f16*)ws;            ws += (size_t)160 * 256 * 2;
    f16* F2     = (f16*)ws;            ws += (size_t)256 * 128 * 2;
    f16* F3     = (f16*)ws;            ws += (size_t)128 * 256 * 2;
    f16* F4     = (f16*)ws;            ws += (size_t)256 * 256 * 2;
    f16* msg    = (f16*)ws;

    hipMemsetAsync(d_ws, 0, zero_bytes, stream);

    pack_weights<<<84, 256, 0, stream>>>(W1, W2, Wh1, Wh2, F1, F2, F3, F4);
    compact_kernel<<<N_EDGES / 256, 256, 0, stream>>>(
        recv, elist, rlist, rankl, deg, cntp);
    prefix_kernel<<<1, 1024, 0, stream>>>(deg, off);
    scatter_kernel<<<1024, 256, 0, stream>>>(elist, rlist, rankl, off, cntp, eidb);
    edge_mlp_mfma<<<512, 512, 0, stream>>>(
        nf, ef, F1, F2, b1, b2, wg, bg, send, recv, eidb, cntp, msg, evals);
    agg_agent_mfma<<<(N_AGENTS + 31) / 32, 1024, 0, stream>>>(
        off, evals, msg, F3, F4, bh1, bh2, Wout, bout, (float*)d_out);
}